// Round 8
// baseline (141.546 us; speedup 1.0000x reference)
//
#include <hip/hip_runtime.h>
#include <math.h>

// B=2, HD=4, H=W=128, KSIZE=7 (K=49), NSP=9, S=64
#define BN   2
#define HDN  4
#define HN   128
#define WN   128
#define KS   7
#define KK   49
#define NSPN 9
#define TPB  128     // 2 fully-autonomous waves; wave owns 16 pixels x 4 heads
#define PIXSTR 60    // gather-buf pixel stride (dwords): 16B-aligned, 2-way banks
#define PBUF (16 * PIXSTR)      // 960 dwords per gather buffer
#define STG  3136    // 4 planes x 784 dwords, per-wave staging (attn in / out)
                     // gather bufs [2][PBUF] OVERLAY stg[0..1919] (disjoint lifetimes)

// Compiler-only memory fence (orders LDS ops the compiler can't see alias
// cross-lane; emits nothing). v8-validated discipline.
#define CFENCE() asm volatile("" ::: "memory")

// v10 = v9 + pipeline depth 2. v9's vmcnt wait (gstore) was 1 compute-phase
// (~400-600cyc) after its issue -- covers an L2 hit, not a miss; ~11us of
// serial latency remained (29us vs 17.5us touch-model floor). v10 keeps TWO
// named q-sets (plane n -> set n&1, +16 VGPR): phase sp issues plane sp+2
// into the set freed last phase, computes sp, then gstores plane sp+1 from
// the other set -> each load has ~2 phases (~800-1200cyc) in flight before
// its wait. Everything else (wide gather 4patch/inst, coalesced attn/out LDS
// staging, pi-from-patch, zero barriers, CFENCE discipline) is v9-identical.
__global__ __launch_bounds__(TPB, 2) void attn_rw10(
    const float* __restrict__ attn,
    const float* __restrict__ sims,
    const int*   __restrict__ sinds,
    float*       __restrict__ out)
{
    __shared__ __align__(16) float smem[2 * STG];       // 25.1 KB
    __shared__ int g_lds[2][16 * NSPN];                 // 1.2 KB

    const int t    = threadIdx.x;
    const int lane = t & 63;
    const int wv   = t >> 6;
    const int bx   = blockIdx.x;
    const int wseg = bx & 3;
    const int hh   = (bx >> 2) & 127;
    const int b    = bx >> 9;
    const int ww0  = wseg * 32 + wv * 16;   // wave's first absolute column

    const int pixL = lane >> 2;             // 0..15 (compute mapping)
    const int hd   = lane & 3;

    const float* simsB = sims + ((size_t)b << 20);
    int hs = hh - 3; hs = max(0, min(HN - KS, hs));
    const int dr = hh - hs;                 // 0..6, block-uniform

    float* stg = smem + wv * STG;           // wave-private staging
    float* pb  = stg;                       // gather bufs overlay stg[0..1919]
    int*   gl  = g_lds[wv];

    // ---- sinds: wave-private 144 ints, one coalesced int4 round ----
    {
        const int* ssrc = sinds + ((b * HN + hh) * WN + ww0) * NSPN;
        if (lane < 36) {
            int4 s;
            __builtin_memcpy(&s, ssrc + lane * 4, 16);
            *(int4*)(gl + lane * 4) = s;
        }
    }
    CFENCE();                               // gl published before issue reads it

    // ---- attn stage LOADS: all 16 float4 first (named scalars) ----
    const size_t hwk   = (size_t)HN * WN * KK;
    const size_t pbase = (size_t)(hh * WN + ww0) * KK;   // 16B-aligned
    const float* aB    = attn + (size_t)b * HDN * hwk + pbase;

    float4 s00,s01,s02,s03, s10,s11,s12,s13, s20,s21,s22,s23, s30,s31,s32,s33;
#define LDP(c, v0, v1, v2, v3) { \
        const float* g_ = aB + (size_t)(c) * hwk; \
        v0 = *(const float4*)(g_ + lane * 4); \
        v1 = *(const float4*)(g_ + 256 + lane * 4); \
        v2 = *(const float4*)(g_ + 512 + lane * 4); \
        v3 = make_float4(0.f, 0.f, 0.f, 0.f); \
        if (lane < 4) v3 = *(const float4*)(g_ + 768 + lane * 4); }
    LDP(0, s00, s01, s02, s03)
    LDP(1, s10, s11, s12, s13)
    LDP(2, s20, s21, s22, s23)
    LDP(3, s30, s31, s32, s33)
#undef LDP

    // ---- wide-gather lane constants (4 patches / instruction) ----
    const int  grp   = min(lane / 14, 3);   // patch slot within instr
    const int  cp    = lane - grp * 14;     // 0..13 active
    const int  grow  = min(cp >> 1, 6);     // row 0..6
    const int  ghalf = cp & 1;              // 0: cols 0-3, 1: cols 3-6
    const bool gact  = lane < 56;
    int pixs[4], wss[4];
    #pragma unroll
    for (int i = 0; i < 4; ++i) {
        pixs[i] = 4 * i + grp;
        wss[i]  = max(0, min(WN - KS, ww0 + pixs[i] - 3));
    }
    const int rowoff = (hs + grow) * WN + ghalf * 3;

    // two named q-sets: plane n lives in set n&1
    float4 qa0, qa1, qa2, qa3, qb0, qb1, qb2, qb3;
#define ISSUE(sp, x0, x1, x2, x3) { \
        int g0_ = gl[pixs[0] * NSPN + (sp)]; \
        int g1_ = gl[pixs[1] * NSPN + (sp)]; \
        int g2_ = gl[pixs[2] * NSPN + (sp)]; \
        int g3_ = gl[pixs[3] * NSPN + (sp)]; \
        if (gact) { \
            __builtin_memcpy(&x0, simsB + ((size_t)g0_ << 14) + rowoff + wss[0], 16); \
            __builtin_memcpy(&x1, simsB + ((size_t)g1_ << 14) + rowoff + wss[1], 16); \
            __builtin_memcpy(&x2, simsB + ((size_t)g2_ << 14) + rowoff + wss[2], 16); \
            __builtin_memcpy(&x3, simsB + ((size_t)g3_ << 14) + rowoff + wss[3], 16); \
        } }
#define GSTORE(buf, x0, x1, x2, x3) { \
        float* d_ = pb + (buf) * PBUF; \
        if (gact) { \
            *(float4*)(d_ + pixs[0] * PIXSTR + grow * 8 + ghalf * 4) = x0; \
            *(float4*)(d_ + pixs[1] * PIXSTR + grow * 8 + ghalf * 4) = x1; \
            *(float4*)(d_ + pixs[2] * PIXSTR + grow * 8 + ghalf * 4) = x2; \
            *(float4*)(d_ + pixs[3] * PIXSTR + grow * 8 + ghalf * 4) = x3; \
        } }

    ISSUE(0, qa0, qa1, qa2, qa3)            // plane 0 -> set A, in flight
    ISSUE(1, qb0, qb1, qb2, qb3)            // plane 1 -> set B, in flight

    // ---- attn stage STORES (vmcnt waits only on their own older loads) ----
#define STP(c, v0, v1, v2, v3) { \
        float* d_ = stg + (c) * 784; \
        *(float4*)(d_ + lane * 4) = v0; \
        *(float4*)(d_ + 256 + lane * 4) = v1; \
        *(float4*)(d_ + 512 + lane * 4) = v2; \
        if (lane < 4) *(float4*)(d_ + 768 + lane * 4) = v3; }
    STP(0, s00, s01, s02, s03)
    STP(1, s10, s11, s12, s13)
    STP(2, s20, s21, s22, s23)
    STP(3, s30, s31, s32, s33)
#undef STP
    CFENCE();                               // cross-lane RAW: stage writes -> a[] reads

    // ---- redistribute attn to a[49] (stride-49 scalar: ~2-way banks) ----
    const int ab = hd * 784 + pixL * KK;
    float a[KK];
    #pragma unroll
    for (int k = 0; k < KK; ++k) a[k] = stg[ab + k];

    // softmax (pure VALU - covers both issued planes' flight)
    {
        float m0 = a[0], m1 = a[1], m2 = a[2], m3 = a[3];
        #pragma unroll
        for (int k = 4; k < KK; k += 4) {
            m0 = fmaxf(m0, a[k]);
            if (k + 1 < KK) m1 = fmaxf(m1, a[k + 1]);
            if (k + 2 < KK) m2 = fmaxf(m2, a[k + 2]);
            if (k + 3 < KK) m3 = fmaxf(m3, a[k + 3]);
        }
        float m = fmaxf(fmaxf(m0, m1), fmaxf(m2, m3));
        #pragma unroll
        for (int k = 0; k < KK; ++k) a[k] = __expf(a[k] - m);
    }
    CFENCE();                               // cross-lane WAR: a[] reads -> overlay write

    GSTORE(0, qa0, qa1, qa2, qa3)           // plane 0 -> buf 0 (set A now free)

    // pi = patch[dr][dc] of own pixel; slot skips dup col 3 (hi.x == lo.w)
    const int wabs  = ww0 + pixL;
    const int wsp   = max(0, min(WN - KS, wabs - 3));
    const int dc    = wabs - wsp;           // 0..6
    const int dcs   = dc + (dc > 3 ? 1 : 0);
    const int pioff = pixL * PIXSTR + dr * 8 + dcs;

    float acc[KK];
    #pragma unroll
    for (int k = 0; k < KK; ++k) acc[k] = 0.0f;

    #define P(k) p[(k) / KS][(k) % KS]

    #pragma unroll
    for (int sp = 0; sp < NSPN; ++sp) {
        const int buf = sp & 1;
        CFENCE();                           // RAW: gstore(prev)->p reads; WAR: reads->later writes

        // depth-2 issue: plane sp+2 into set sp&1 (freed by last phase's gstore)
        if (sp + 2 < NSPN) {
            if ((sp & 1) == 0) { ISSUE(sp + 2, qa0, qa1, qa2, qa3) }
            else               { ISSUE(sp + 2, qb0, qb1, qb2, qb3) }
        }

        // p patch: 14 x b128 (lo/hi per row); 4 hd-lanes broadcast, pixL 2-way
        float p[KS][KS];
        const float* prow = pb + buf * PBUF + pixL * PIXSTR;
        #pragma unroll
        for (int r = 0; r < KS; ++r) {
            float4 lo = *(const float4*)(prow + r * 8);      // cols 0-3
            float4 hi = *(const float4*)(prow + r * 8 + 4);  // cols 3-6
            p[r][0] = lo.x; p[r][1] = lo.y; p[r][2] = lo.z; p[r][3] = lo.w;
            p[r][4] = hi.y; p[r][5] = hi.z; p[r][6] = hi.w;
        }

        // denom: 4-way split FMA chains
        float d0 = 0.f, d1 = 0.f, d2 = 0.f, d3 = 0.f;
        #pragma unroll
        for (int k = 0; k < 48; k += 4) {
            d0 = fmaf(a[k + 0], P(k + 0), d0);
            d1 = fmaf(a[k + 1], P(k + 1), d1);
            d2 = fmaf(a[k + 2], P(k + 2), d2);
            d3 = fmaf(a[k + 3], P(k + 3), d3);
        }
        d0 = fmaf(a[48], P(48), d0);
        float d = (d0 + d1) + (d2 + d3);

        float pi   = pb[buf * PBUF + pioff];
        float coef = pi * __builtin_amdgcn_rcpf(d + 1e-10f);

        #pragma unroll
        for (int k = 0; k < KK; ++k) acc[k] = fmaf(coef, P(k), acc[k]);

        // gstore plane sp+1 from set (sp+1)&1 (issued ~2 phases ago)
        if (sp + 1 < NSPN) {
            if (((sp + 1) & 1) == 0) { GSTORE(buf ^ 1, qa0, qa1, qa2, qa3) }
            else                     { GSTORE(buf ^ 1, qb0, qb1, qb2, qb3) }
        }
    }
    #undef P
#undef ISSUE
#undef GSTORE

    // ---- out: scalar LDS stage (overwrites gather bufs) -> float4 stores ----
    CFENCE();                               // cross-lane WAR: last p reads -> out-stage writes
    #pragma unroll
    for (int k = 0; k < KK; ++k) stg[ab + k] = a[k] * acc[k];
    CFENCE();                               // cross-lane RAW: out writes -> float4 reads

    float* oB = out + (size_t)b * HDN * hwk + pbase;
    #pragma unroll
    for (int c = 0; c < 4; ++c) {
        const float* s_ = stg + c * 784;
        float*       o_ = oB + (size_t)c * hwk;
        float4 z0 = *(const float4*)(s_ + lane * 4);
        float4 z1 = *(const float4*)(s_ + 256 + lane * 4);
        float4 z2 = *(const float4*)(s_ + 512 + lane * 4);
        *(float4*)(o_ + lane * 4) = z0;
        *(float4*)(o_ + 256 + lane * 4) = z1;
        *(float4*)(o_ + 512 + lane * 4) = z2;
        if (lane < 4) {
            float4 z3 = *(const float4*)(s_ + 768 + lane * 4);
            *(float4*)(o_ + 768 + lane * 4) = z3;
        }
    }
}

extern "C" void kernel_launch(void* const* d_in, const int* in_sizes, int n_in,
                              void* d_out, int out_size, void* d_ws, size_t ws_size,
                              hipStream_t stream) {
    const float* attn  = (const float*)d_in[0];
    const float* sims  = (const float*)d_in[1];
    const int*   sinds = (const int*)d_in[2];
    float*       outp  = (float*)d_out;

    // blocks: b(2) x hh(128) x wseg(4) = 1024, 2 autonomous waves each
    const int blocks = BN * HN * (WN / 32);
    attn_rw10<<<blocks, TPB, 0, stream>>>(attn, sims, sinds, outp);
}

// Round 9
// 98.721 us; speedup vs baseline: 1.4338x; 1.4338x over previous
//
#include <hip/hip_runtime.h>
#include <math.h>

// B=2, HD=4, H=W=128, KSIZE=7 (K=49), NSP=9, S=64
#define BN   2
#define HDN  4
#define HN   128
#define WN   128
#define KS   7
#define KK   49
#define NSPN 9
#define TPB  128     // 2 fully-autonomous waves; wave owns 16 pixels x 4 heads
#define ISTR 260     // DMA instr-slot stride (dwords): 1024B data + 16B pad; 2-way banks
#define GBUF (4 * ISTR)          // 1040 dwords per plane buffer (4 DMA instrs)
#define NBUF 3                   // plane buffers in flight
#define STGD 1568                // 2-plane chunked attn/out staging (dwords)
#define WREG (STGD + NBUF * GBUF)  // 4688 dwords per wave (18.75 KB)

// Compiler-only memory fence (v8-validated discipline for barrier-free
// cross-lane LDS reuse; emits nothing).
#define CFENCE() asm volatile("" ::: "memory")

// global->LDS DMA: dest = uniform base + lane*16 (m104 rule), per-lane source.
#define GLDS(srcp, ldsp) \
    __builtin_amdgcn_global_load_lds( \
        (const __attribute__((address_space(1))) void*)(srcp), \
        (__attribute__((address_space(3))) void*)(ldsp), 16, 0, 0)

// v11: depth-3 gather pipeline at ZERO register cost via global_load_lds.
// v10 proved in-flight gather data in VGPRs spills (128-VGPR cliff, +180MB
// scratch). DMA keeps in-flight data in the vmcnt queue: 3 plane buffers,
// counted s_waitcnt vmcnt(8) per phase (planes sp+1,sp+2 never drained, T4),
// issue plane sp+3 after the phase's ds_reads. Gather LDS layout is lane-
// order ([instr][lane][4dw], slot stride 260dw -> 2-way banks): exactly the
// contiguous dest the DMA requires. LDS forces chunked 2-plane attn/out
// staging (v7 shape + the CFENCE at every cross-lane reuse v7 lacked).
__global__ __launch_bounds__(TPB, 2) void attn_rw11(
    const float* __restrict__ attn,
    const float* __restrict__ sims,
    const int*   __restrict__ sinds,
    float*       __restrict__ out)
{
    __shared__ __align__(16) float smem[2 * WREG];      // 37.5 KB
    __shared__ int g_lds[2][16 * NSPN];                 // 1.2 KB

    const int t    = threadIdx.x;
    const int lane = t & 63;
    const int wv   = t >> 6;
    const int bx   = blockIdx.x;
    const int wseg = bx & 3;
    const int hh   = (bx >> 2) & 127;
    const int b    = bx >> 9;
    const int ww0  = wseg * 32 + wv * 16;   // wave's first absolute column

    const int pixL = lane >> 2;             // 0..15 (compute mapping)
    const int hd   = lane & 3;

    const float* simsB = sims + ((size_t)b << 20);
    int hs = hh - 3; hs = max(0, min(HN - KS, hs));
    const int dr = hh - hs;                 // 0..6, block-uniform

    float* stg = smem + wv * WREG;          // [0..1567] 2-plane staging
    float* pbw = stg + STGD;                // [NBUF][GBUF] DMA gather buffers
    int*   gl  = g_lds[wv];

    // ---- sinds: one coalesced int4 round ----
    int4 sreg = make_int4(0, 0, 0, 0);
    {
        const int* ssrc = sinds + ((b * HN + hh) * WN + ww0) * NSPN;
        if (lane < 36) __builtin_memcpy(&sreg, ssrc + lane * 4, 16);
    }

    // ---- attn loads: all 16 float4 first (named scalars, prologue-only) ----
    const size_t hwk   = (size_t)HN * WN * KK;
    const size_t pbase = (size_t)(hh * WN + ww0) * KK;   // 16B-aligned
    const float* aB    = attn + (size_t)b * HDN * hwk + pbase;

    float4 s00,s01,s02,s03, s10,s11,s12,s13, s20,s21,s22,s23, s30,s31,s32,s33;
#define LDP(c, v0, v1, v2, v3) { \
        const float* g_ = aB + (size_t)(c) * hwk; \
        v0 = *(const float4*)(g_ + lane * 4); \
        v1 = *(const float4*)(g_ + 256 + lane * 4); \
        v2 = *(const float4*)(g_ + 512 + lane * 4); \
        v3 = make_float4(0.f, 0.f, 0.f, 0.f); \
        if (lane < 4) v3 = *(const float4*)(g_ + 768 + lane * 4); }
    LDP(0, s00, s01, s02, s03)
    LDP(1, s10, s11, s12, s13)
    LDP(2, s20, s21, s22, s23)
    LDP(3, s30, s31, s32, s33)
#undef LDP

    if (lane < 36) *(int4*)(gl + lane * 4) = sreg;   // publish sinds
    CFENCE();                                        // gl ready before ISSUE reads

    // ---- wide-gather lane constants (4 patches / DMA instruction) ----
    const int grp   = min(lane / 14, 3);    // patch slot within instr
    const int cp    = lane - grp * 14;
    const int grow  = min(cp >> 1, 6);      // row 0..6 (clamped: lanes 56-63 benign)
    const int ghalf = cp & 1;               // 0: cols 0-3, 1: cols 3-6
    const int pixs0 = grp,      pixs1 = 4 + grp;
    const int pixs2 = 8 + grp,  pixs3 = 12 + grp;
    const int wss0 = max(0, min(WN - KS, ww0 + pixs0 - 3));
    const int wss1 = max(0, min(WN - KS, ww0 + pixs1 - 3));
    const int wss2 = max(0, min(WN - KS, ww0 + pixs2 - 3));
    const int wss3 = max(0, min(WN - KS, ww0 + pixs3 - 3));
    const int rowoff = (hs + grow) * WN + ghalf * 3;

#define ISSUE(sp, buf) { \
        int g0_ = gl[pixs0 * NSPN + (sp)]; \
        int g1_ = gl[pixs1 * NSPN + (sp)]; \
        int g2_ = gl[pixs2 * NSPN + (sp)]; \
        int g3_ = gl[pixs3 * NSPN + (sp)]; \
        float* bb_ = pbw + (buf) * GBUF; \
        GLDS(simsB + ((size_t)g0_ << 14) + rowoff + wss0, bb_); \
        GLDS(simsB + ((size_t)g1_ << 14) + rowoff + wss1, bb_ + ISTR); \
        GLDS(simsB + ((size_t)g2_ << 14) + rowoff + wss2, bb_ + 2 * ISTR); \
        GLDS(simsB + ((size_t)g3_ << 14) + rowoff + wss3, bb_ + 3 * ISTR); }

    ISSUE(0, 0)                              // planes 0..2 in flight (12 DMAs,
    ISSUE(1, 1)                              // zero VGPR held)
    ISSUE(2, 2)

    // ---- chunked attn staging (2 LDS plane-slots) + a[] reads ----
    float a[KK];
#define STP(slot, v0, v1, v2, v3) { \
        float* d_ = stg + (slot) * 784; \
        *(float4*)(d_ + lane * 4) = v0; \
        *(float4*)(d_ + 256 + lane * 4) = v1; \
        *(float4*)(d_ + 512 + lane * 4) = v2; \
        if (lane < 4) *(float4*)(d_ + 768 + lane * 4) = v3; }
    STP(0, s00, s01, s02, s03)               // waits vmcnt for attn regs only
    STP(1, s10, s11, s12, s13)               // (12 younger DMAs stay in flight)
    CFENCE();                                // RAW: stage writes -> a[] reads
    if (hd < 2) {
        const int ab_ = hd * 784 + pixL * KK;   // stride-49: conflict-free
        #pragma unroll
        for (int k = 0; k < KK; ++k) a[k] = stg[ab_ + k];
    }
    CFENCE();                                // WAR: a[] reads -> slot overwrite
    STP(0, s20, s21, s22, s23)
    STP(1, s30, s31, s32, s33)
    CFENCE();                                // RAW
    if (hd >= 2) {
        const int ab_ = (hd - 2) * 784 + pixL * KK;
        #pragma unroll
        for (int k = 0; k < KK; ++k) a[k] = stg[ab_ + k];
    }
#undef STP

    // softmax (pure VALU - covers the 3 in-flight planes)
    {
        float m0 = a[0], m1 = a[1], m2 = a[2], m3 = a[3];
        #pragma unroll
        for (int k = 4; k < KK; k += 4) {
            m0 = fmaxf(m0, a[k]);
            if (k + 1 < KK) m1 = fmaxf(m1, a[k + 1]);
            if (k + 2 < KK) m2 = fmaxf(m2, a[k + 2]);
            if (k + 3 < KK) m3 = fmaxf(m3, a[k + 3]);
        }
        float m = fmaxf(fmaxf(m0, m1), fmaxf(m2, m3));
        #pragma unroll
        for (int k = 0; k < KK; ++k) a[k] = __expf(a[k] - m);
    }

    // ---- compute-view constants ----
    const int ipix    = pixL >> 2;           // which DMA instr slot
    const int grpv    = pixL & 3;            // which patch within it
    const int pixbase = ipix * ISTR + grpv * 56;   // 14 lanes x 4 dwords
    const int wabs    = ww0 + pixL;
    const int wsp     = max(0, min(WN - KS, wabs - 3));
    const int dc      = wabs - wsp;          // 0..6
    const int pidw    = dr * 8 + dc + (dc > 3 ? 1 : 0);   // pi slot (dup col3 skip)

    float acc[KK];
    #pragma unroll
    for (int k = 0; k < KK; ++k) acc[k] = 0.0f;

#define P_(k) p[(k) / KS][(k) % KS]
// counted-vmcnt phase: wait plane sp (never drain to 0 mid-loop), read patch,
// issue plane sp+NBUF into the freed buffer, FMA.
#define PHASE(sp, vmlit) { \
        asm volatile("s_waitcnt vmcnt(" vmlit ")" ::: "memory"); \
        const float* pp_ = pbw + ((sp) % NBUF) * GBUF + pixbase; \
        float p[KS][KS]; \
        _Pragma("unroll") \
        for (int r = 0; r < KS; ++r) { \
            float4 lo = *(const float4*)(pp_ + r * 8); \
            float4 hi = *(const float4*)(pp_ + r * 8 + 4); \
            p[r][0] = lo.x; p[r][1] = lo.y; p[r][2] = lo.z; p[r][3] = lo.w; \
            p[r][4] = hi.y; p[r][5] = hi.z; p[r][6] = hi.w; } \
        float pi_ = pp_[pidw]; \
        CFENCE();                            /* reads before overwrite-issue */ \
        if ((sp) + NBUF < NSPN) { ISSUE((sp) + NBUF, (sp) % NBUF) } \
        float d0 = 0.f, d1 = 0.f, d2 = 0.f, d3 = 0.f; \
        _Pragma("unroll") \
        for (int k = 0; k < 48; k += 4) { \
            d0 = fmaf(a[k + 0], P_(k + 0), d0); \
            d1 = fmaf(a[k + 1], P_(k + 1), d1); \
            d2 = fmaf(a[k + 2], P_(k + 2), d2); \
            d3 = fmaf(a[k + 3], P_(k + 3), d3); } \
        d0 = fmaf(a[48], P_(48), d0); \
        float dd_ = (d0 + d1) + (d2 + d3); \
        float coef_ = pi_ * __builtin_amdgcn_rcpf(dd_ + 1e-10f); \
        _Pragma("unroll") \
        for (int k = 0; k < KK; ++k) acc[k] = fmaf(coef_, P_(k), acc[k]); }

    PHASE(0, "8") PHASE(1, "8") PHASE(2, "8")
    PHASE(3, "8") PHASE(4, "8") PHASE(5, "8")
    PHASE(6, "8") PHASE(7, "4") PHASE(8, "0")
#undef PHASE
#undef P_
#undef ISSUE

    // ---- out: chunked scalar LDS stage -> coalesced float4 stores ----
    float* oB = out + (size_t)b * HDN * hwk + pbase;
#define OUTC(c, slot) { \
        const float* s_ = stg + (slot) * 784; \
        float*       o_ = oB + (size_t)(c) * hwk; \
        float4 z0 = *(const float4*)(s_ + lane * 4); \
        float4 z1 = *(const float4*)(s_ + 256 + lane * 4); \
        float4 z2 = *(const float4*)(s_ + 512 + lane * 4); \
        *(float4*)(o_ + lane * 4) = z0; \
        *(float4*)(o_ + 256 + lane * 4) = z1; \
        *(float4*)(o_ + 512 + lane * 4) = z2; \
        if (lane < 4) { \
            float4 z3 = *(const float4*)(s_ + 768 + lane * 4); \
            *(float4*)(o_ + 768 + lane * 4) = z3; } }

    CFENCE();
    if (hd < 2) {
        const int ab_ = hd * 784 + pixL * KK;
        #pragma unroll
        for (int k = 0; k < KK; ++k) stg[ab_ + k] = a[k] * acc[k];
    }
    CFENCE();                                // RAW: writes -> coalesced reads
    OUTC(0, 0) OUTC(1, 1)
    CFENCE();                                // WAR: reads -> slot overwrite
    if (hd >= 2) {
        const int ab_ = (hd - 2) * 784 + pixL * KK;
        #pragma unroll
        for (int k = 0; k < KK; ++k) stg[ab_ + k] = a[k] * acc[k];
    }
    CFENCE();
    OUTC(2, 0) OUTC(3, 1)
#undef OUTC
}

extern "C" void kernel_launch(void* const* d_in, const int* in_sizes, int n_in,
                              void* d_out, int out_size, void* d_ws, size_t ws_size,
                              hipStream_t stream) {
    const float* attn  = (const float*)d_in[0];
    const float* sims  = (const float*)d_in[1];
    const int*   sinds = (const int*)d_in[2];
    float*       outp  = (float*)d_out;

    // blocks: b(2) x hh(128) x wseg(4) = 1024, 2 autonomous waves each
    const int blocks = BN * HN * (WN / 32);
    attn_rw11<<<blocks, TPB, 0, stream>>>(attn, sims, sinds, outp);
}